// Round 6
// baseline (532.865 us; speedup 1.0000x reference)
//
#include <hip/hip_runtime.h>
#include <math.h>

#define S0 3600
#define S1 720
#define S2 144
#define S3 36
#define S4 9
#define NEGF (-1e30f)

// ---- workspace layout (bytes). Peak 74.72 MB (proven in rounds 2-5).
static constexpr size_t OFF_X0  = 0;                                    // f32 [3600*3600] = 51,840,000
static constexpr size_t OFF_M0B = (size_t)S0 * S0 * 4;                  // u32 bitfield    = 1,620,000
static constexpr size_t OFF_Y1  = OFF_M0B + 1620000;                    // f32 [720*720*10] @53,460,000
static constexpr size_t OFF_M1  = OFF_Y1 + (size_t)S1 * S1 * 10 * 4;    // u8  [720*720]    @74,196,000 (ends 74,714,400)
// aliased into dead x0 region (used from conv2 onward):
static constexpr size_t OFF_Y2  = 0;                                    // f32 [144*144*64]  = 5,308,416
static constexpr size_t OFF_M2  = OFF_Y2 + (size_t)S2 * S2 * 64 * 4;    // u8  [144*144]
static constexpr size_t OFF_Y3  = OFF_M2 + 20736;                       // f32 [36*36*128] @5,329,152
static constexpr size_t OFF_M3  = OFF_Y3 + (size_t)S3 * S3 * 128 * 4;   // u8  [36*36]     @5,992,704
static constexpr size_t OFF_Y4  = OFF_M3 + 1296;                        // f32 [9*9*256]   @5,994,000
static constexpr size_t OFF_H1  = OFF_Y4 + (size_t)S4 * S4 * 256 * 4;   // f32 [32]        @6,076,944
static constexpr size_t OFF_P4  = 6077200;                              // f32 [81*5*16*256] = 6,635,520 (ends 12.7 MB)

__device__ __forceinline__ float eluf(float x) { return x > 0.f ? x : expm1f(x); }
__device__ __forceinline__ void fma4(float4& a, float s, const float4& w) {
    a.x = fmaf(s, w.x, a.x); a.y = fmaf(s, w.y, a.y);
    a.z = fmaf(s, w.z, a.z); a.w = fmaf(s, w.w, a.w);
}

// ---- scatter points onto dense grid -----------------------------------------
__global__ __launch_bounds__(256) void k_scatter(const int* __restrict__ coords,
                                                 const float* __restrict__ feats,
                                                 float* __restrict__ x0,
                                                 unsigned* __restrict__ m0b, int P) {
    int i = blockIdx.x * 256 + threadIdx.x;
    if (i >= P) return;
    int r = coords[2 * i], c = coords[2 * i + 1];
    int idx = r * S0 + c;
    atomicAdd(&x0[idx], feats[i]);
    atomicOr(&m0b[idx >> 5], 1u << (idx & 31));
}

// ---- layer 1: sparse conv 5x5 1->10 + ELU + maxpool5 (mask-bitfield-driven) -
__global__ __launch_bounds__(256) void k_l1(const float* __restrict__ x0,
                                            const unsigned* __restrict__ m0b,
                                            const float* __restrict__ w1,
                                            float* __restrict__ y1,
                                            unsigned char* __restrict__ m1) {
    __shared__ float w1s[250];
    int tid = threadIdx.x;
    if (tid < 250) w1s[tid] = w1[tid];
    __syncthreads();
    int t = blockIdx.x * 256 + tid;       // grid exact: 720*720 = 518400
    int pr = t / S1, pc = t % S1;
    int r0 = pr * 5 - 2, c0 = pc * 5 - 2; // 9x9 patch origin
    unsigned rows[9];
#pragma unroll
    for (int rr = 0; rr < 9; rr++) {
        unsigned bits = 0;
        int gr = r0 + rr;
        if (gr >= 0 && gr < S0) {
            int cs = c0 < 0 ? 0 : c0;
            int ce = c0 + 8 > S0 - 1 ? S0 - 1 : c0 + 8;
            int span = ce - cs;
            size_t i0 = (size_t)gr * S0 + cs;
            unsigned sh = (unsigned)(i0 & 31);
            unsigned long long two = (unsigned long long)m0b[i0 >> 5] >> sh;
            if ((int)sh + span >= 32)
                two |= (unsigned long long)m0b[(i0 >> 5) + 1] << (32 - sh);
            bits = (unsigned)(two & ((1u << (span + 1)) - 1));
            bits <<= (cs - c0);
        }
        rows[rr] = bits;
    }
    unsigned any25 = 0;
#pragma unroll
    for (int dy = 0; dy < 5; dy++) any25 |= (rows[2 + dy] >> 2) & 0x1Fu;
    float* yo = &y1[(size_t)t * 10];
    if (!any25) {
#pragma unroll
        for (int q = 0; q < 5; q++) ((float2*)yo)[q] = make_float2(0.f, 0.f);
        m1[t] = 0;
        return;
    }
    float2 mx[5];
#pragma unroll
    for (int q = 0; q < 5; q++) mx[q] = make_float2(NEGF, NEGF);
    for (int dy = 0; dy < 5; dy++) {
        unsigned crow = (rows[2 + dy] >> 2) & 0x1Fu;
        while (crow) {
            int dx = __ffs(crow) - 1; crow &= crow - 1;
            float2 acc[5];
#pragma unroll
            for (int q = 0; q < 5; q++) acc[q] = make_float2(0.f, 0.f);
#pragma unroll
            for (int ky = 0; ky < 5; ky++) {
                unsigned nrow = (rows[dy + ky] >> dx) & 0x1Fu;
                size_t rowbase = (size_t)(r0 + dy + ky) * S0 + (c0 + dx);
                while (nrow) {
                    int kx = __ffs(nrow) - 1; nrow &= nrow - 1;
                    float xv = x0[rowbase + kx];
                    const float2* wp = (const float2*)&w1s[(ky * 5 + kx) * 10];
#pragma unroll
                    for (int q = 0; q < 5; q++) {
                        float2 w = wp[q];
                        acc[q].x = fmaf(xv, w.x, acc[q].x);
                        acc[q].y = fmaf(xv, w.y, acc[q].y);
                    }
                }
            }
#pragma unroll
            for (int q = 0; q < 5; q++) {
                mx[q].x = fmaxf(mx[q].x, acc[q].x);
                mx[q].y = fmaxf(mx[q].y, acc[q].y);
            }
        }
    }
#pragma unroll
    for (int q = 0; q < 5; q++) {
        float2 o;
        o.x = eluf(mx[q].x); o.y = eluf(mx[q].y);
        ((float2*)yo)[q] = o;
    }
    m1[t] = 1;
}

// ---- layer 2: fused conv 5x5 10->64 (cell-gated) + ELU + maxpool5 -----------
__global__ __launch_bounds__(64) void k_l2(const float* __restrict__ y1,
                                           const unsigned char* __restrict__ m1,
                                           const float* __restrict__ w2,
                                           float* __restrict__ y2,
                                           unsigned char* __restrict__ m2) {
    __shared__ float win[81 * 12];
    __shared__ unsigned char sm[81];
    int b = blockIdx.x;
    int pr = b / S2, pc = b % S2;
    int r0 = pr * 5 - 2, c0 = pc * 5 - 2;
    int tid = threadIdx.x;
    for (int k = tid; k < 81; k += 64) {
        int gr = r0 + k / 9, gc = c0 + k % 9;
        bool ok = (gr >= 0 && gr < S1 && gc >= 0 && gc < S1);
        sm[k] = ok ? m1[gr * S1 + gc] : (unsigned char)0;
        float* dst = &win[k * 12];
        if (ok) {
            const float2* src = (const float2*)&y1[((size_t)gr * S1 + gc) * 10];
#pragma unroll
            for (int q = 0; q < 5; q++) ((float2*)dst)[q] = src[q];
        } else {
#pragma unroll
            for (int q = 0; q < 5; q++) ((float2*)dst)[q] = make_float2(0.f, 0.f);
        }
        dst[10] = 0.f; dst[11] = 0.f;
    }
    __syncthreads();
    int c = tid;
    unsigned mbits = 0;
#pragma unroll
    for (int cell = 0; cell < 25; cell++) {
        if (sm[(2 + cell / 5) * 9 + (2 + cell % 5)]) mbits |= (1u << cell);
    }
    mbits = (unsigned)__builtin_amdgcn_readfirstlane((int)mbits);
    float acc[25];
#pragma unroll
    for (int i = 0; i < 25; i++) acc[i] = 0.f;
    for (int t5 = 0; t5 < 25; t5++) {
        float w[10];
#pragma unroll
        for (int ci = 0; ci < 10; ci++) w[ci] = w2[(t5 * 10 + ci) * 64 + c];
        int base = (t5 / 5) * 9 + (t5 % 5);
#pragma unroll
        for (int cell = 0; cell < 25; cell++) {
            if (mbits & (1u << cell)) {
                const float4* xp = (const float4*)&win[(base + (cell / 5) * 9 + (cell % 5)) * 12];
                float4 xa = xp[0], xb = xp[1], xc = xp[2];
                float a = acc[cell];
                a = fmaf(xa.x, w[0], a); a = fmaf(xa.y, w[1], a);
                a = fmaf(xa.z, w[2], a); a = fmaf(xa.w, w[3], a);
                a = fmaf(xb.x, w[4], a); a = fmaf(xb.y, w[5], a);
                a = fmaf(xb.z, w[6], a); a = fmaf(xb.w, w[7], a);
                a = fmaf(xc.x, w[8], a); a = fmaf(xc.y, w[9], a);
                acc[cell] = a;
            }
        }
    }
    float mx = NEGF;
#pragma unroll
    for (int cell = 0; cell < 25; cell++)
        if (mbits & (1u << cell)) mx = fmaxf(mx, acc[cell]);
    bool any = (mbits != 0);
    y2[((size_t)pr * S2 + pc) * 64 + c] = any ? eluf(mx) : 0.f;
    if (c == 0) m2[pr * S2 + pc] = any ? 1 : 0;
}

// ---- layer 3: fused conv 5x5 64->128 + ELU + maxpool4 -> 36^2 ---------------
// 256 thr/block; thread = (co-quad 0..31, cell-row 0..3, ci-half 0..1).
// K per thread = 800 (12800 FMA); halves summed via LDS; 5184 waves total.
__global__ __launch_bounds__(256) void k_l3(const float* __restrict__ y2,
                                            const unsigned char* __restrict__ m2,
                                            const float* __restrict__ w3,
                                            float* __restrict__ y3,
                                            unsigned char* __restrict__ m3) {
    __shared__ float win[8 * 8 * 64];    // 16 KB, [cell(r*8+c)][ci]
    __shared__ float part[2][16][128];   // 16 KB, [ci-half][cell][co]
    __shared__ unsigned char sm[16];
    int b = blockIdx.x;                  // 0..1295
    int ppr = b / S3, ppc = b % S3;
    int r0 = ppr * 4 - 2, c0 = ppc * 4 - 2;
    int tid = threadIdx.x;
    float4* win4 = (float4*)win;
    for (int k = tid; k < 1024; k += 256) {
        int cellk = k >> 4, q = k & 15;
        int gr = r0 + (cellk >> 3), gc = c0 + (cellk & 7);
        float4 v = make_float4(0.f, 0.f, 0.f, 0.f);
        if (gr >= 0 && gr < S2 && gc >= 0 && gc < S2)
            v = ((const float4*)y2)[((size_t)gr * S2 + gc) * 16 + q];
        win4[k] = v;
    }
    if (tid < 16) sm[tid] = m2[(ppr * 4 + (tid >> 2)) * S2 + ppc * 4 + (tid & 3)];
    __syncthreads();
    int cq = tid & 31;                   // co-quad
    int pr = (tid >> 5) & 3;             // cell row
    int kh = tid >> 7;                   // ci half
    int co4 = cq * 4;
    float4 acc[4];
#pragma unroll
    for (int i = 0; i < 4; i++) acc[i] = make_float4(0.f, 0.f, 0.f, 0.f);
#pragma unroll 1
    for (int t5 = 0; t5 < 25; t5++) {
        int ky = t5 / 5, kx = t5 % 5;
        int rowbase = (pr + ky) * 8 + kx;                    // + pc
        const float4* wq = (const float4*)&w3[(size_t)(t5 * 64 + kh * 32) * 128 + co4];
#pragma unroll
        for (int ci4 = 0; ci4 < 8; ci4++) {
            int cig = kh * 8 + ci4;
            float4 xv0 = win4[(rowbase + 0) * 16 + cig];
            float4 xv1 = win4[(rowbase + 1) * 16 + cig];
            float4 xv2 = win4[(rowbase + 2) * 16 + cig];
            float4 xv3 = win4[(rowbase + 3) * 16 + cig];
            float4 w0 = wq[(ci4 * 4 + 0) * 32];
            float4 w1 = wq[(ci4 * 4 + 1) * 32];
            float4 w2v = wq[(ci4 * 4 + 2) * 32];
            float4 w3v = wq[(ci4 * 4 + 3) * 32];
            fma4(acc[0], xv0.x, w0); fma4(acc[0], xv0.y, w1); fma4(acc[0], xv0.z, w2v); fma4(acc[0], xv0.w, w3v);
            fma4(acc[1], xv1.x, w0); fma4(acc[1], xv1.y, w1); fma4(acc[1], xv1.z, w2v); fma4(acc[1], xv1.w, w3v);
            fma4(acc[2], xv2.x, w0); fma4(acc[2], xv2.y, w1); fma4(acc[2], xv2.z, w2v); fma4(acc[2], xv2.w, w3v);
            fma4(acc[3], xv3.x, w0); fma4(acc[3], xv3.y, w1); fma4(acc[3], xv3.z, w2v); fma4(acc[3], xv3.w, w3v);
        }
    }
#pragma unroll
    for (int pc = 0; pc < 4; pc++)
        *(float4*)&part[kh][pr * 4 + pc][co4] = acc[pc];
    __syncthreads();
    bool any = false;
#pragma unroll
    for (int i = 0; i < 16; i++) any |= (sm[i] != 0);
    if (tid < 128) {
        int co = tid;
        float m = NEGF;
#pragma unroll
        for (int cell = 0; cell < 16; cell++) {
            if (sm[cell]) {
                float v = part[0][cell][co] + part[1][cell][co];
                m = fmaxf(m, v);
            }
        }
        y3[(size_t)b * 128 + co] = any ? eluf(m) : 0.f;
    }
    if (tid == 0) m3[b] = any ? 1 : 0;
}

// ---- layer 4 conv, K-split over ky: block = (pool cell, ky) -----------------
__global__ __launch_bounds__(256) void k_l4(const float* __restrict__ y3,
                                            const float* __restrict__ w4,
                                            float* __restrict__ part) {
    __shared__ float win[4 * 8 * 128];  // 16 KB
    int b = blockIdx.x;                  // 0..404
    int p = b / 5, ky = b % 5;
    int ppr = p / S4, ppc = p % S4;
    int r0 = ppr * 4 - 2 + ky, c0 = ppc * 4 - 2;
    int tid = threadIdx.x;
    float4* win4 = (float4*)win;
    for (int k = tid; k < 1024; k += 256) {
        int cellk = k >> 5, q = k & 31;  // cellk = rr*8+cc, rr 0..3
        int gr = r0 + (cellk >> 3), gc = c0 + (cellk & 7);
        float4 v = make_float4(0.f, 0.f, 0.f, 0.f);
        if (gr >= 0 && gr < S3 && gc >= 0 && gc < S3)
            v = ((const float4*)y3)[((size_t)gr * S3 + gc) * 32 + q];
        win4[k] = v;
    }
    __syncthreads();
    int cq = tid & 63, pr = tid >> 6;    // co-quad 0..63, cell-row 0..3
    int co4 = cq * 4;
    float4 acc[4];
#pragma unroll
    for (int i = 0; i < 4; i++) acc[i] = make_float4(0.f, 0.f, 0.f, 0.f);
#pragma unroll 1
    for (int kx = 0; kx < 5; kx++) {
        int rowbase = pr * 8 + kx;                           // + pc
        const float4* wq = (const float4*)&w4[(size_t)((ky * 5 + kx) * 128) * 256 + co4];
#pragma unroll 4
        for (int ci4 = 0; ci4 < 32; ci4++) {
            float4 xv0 = win4[(rowbase + 0) * 32 + ci4];
            float4 xv1 = win4[(rowbase + 1) * 32 + ci4];
            float4 xv2 = win4[(rowbase + 2) * 32 + ci4];
            float4 xv3 = win4[(rowbase + 3) * 32 + ci4];
            float4 w0 = wq[(ci4 * 4 + 0) * 64];
            float4 w1 = wq[(ci4 * 4 + 1) * 64];
            float4 w2v = wq[(ci4 * 4 + 2) * 64];
            float4 w3v = wq[(ci4 * 4 + 3) * 64];
            fma4(acc[0], xv0.x, w0); fma4(acc[0], xv0.y, w1); fma4(acc[0], xv0.z, w2v); fma4(acc[0], xv0.w, w3v);
            fma4(acc[1], xv1.x, w0); fma4(acc[1], xv1.y, w1); fma4(acc[1], xv1.z, w2v); fma4(acc[1], xv1.w, w3v);
            fma4(acc[2], xv2.x, w0); fma4(acc[2], xv2.y, w1); fma4(acc[2], xv2.z, w2v); fma4(acc[2], xv2.w, w3v);
            fma4(acc[3], xv3.x, w0); fma4(acc[3], xv3.y, w1); fma4(acc[3], xv3.z, w2v); fma4(acc[3], xv3.w, w3v);
        }
    }
#pragma unroll
    for (int pc = 0; pc < 4; pc++) {
        int cell = pr * 4 + pc;
        *(float4*)&part[(((size_t)p * 5 + ky) * 16 + cell) * 256 + co4] = acc[pc];
    }
}

// ---- layer 4 reduce K-partials + ELU + maxpool4 -> 9^2 ----------------------
__global__ __launch_bounds__(256) void k_p4(const float* __restrict__ part,
                                            const unsigned char* __restrict__ m3,
                                            float* __restrict__ y4) {
    int p = blockIdx.x;                  // 0..80
    int co = threadIdx.x;                // 0..255
    int ppr = p / S4, ppc = p % S4;
    float mx = NEGF;
    bool any = false;
    for (int cell = 0; cell < 16; cell++) {
        int site = (ppr * 4 + (cell >> 2)) * S3 + ppc * 4 + (cell & 3);
        if (!m3[site]) continue;
        any = true;
        float s = 0.f;
#pragma unroll
        for (int ky = 0; ky < 5; ky++)
            s += part[(((size_t)p * 5 + ky) * 16 + cell) * 256 + co];
        mx = fmaxf(mx, s);
    }
    y4[(size_t)p * 256 + co] = any ? eluf(mx) : 0.f;
}

// ---- fc1 (deterministic): 32 blocks, block j computes h1[j] -----------------
__global__ __launch_bounds__(256) void k_fc1(const float* __restrict__ y4,
                                             const float* __restrict__ fc1_w,
                                             float* __restrict__ h1) {
    __shared__ float part[256];
    int j = blockIdx.x;                    // 0..31
    int tid = threadIdx.x;
    float s = 0.f;
    for (int i = tid; i < 256 * 81; i += 256) {
        int c = i / 81, rem = i % 81;      // NCHW flatten: i = c*81 + h*9 + w
        s = fmaf(y4[(size_t)rem * 256 + c], fc1_w[(size_t)i * 32 + j], s);
    }
    part[tid] = s;
    __syncthreads();
    for (int off = 128; off > 0; off >>= 1) {
        if (tid < off) part[tid] += part[tid + off];
        __syncthreads();
    }
    if (tid == 0) h1[j] = part[0];
}

// ---- fc2 + softmax ----------------------------------------------------------
__global__ __launch_bounds__(64) void k_fc2(const float* __restrict__ h1,
                                            const float* __restrict__ fc1_b,
                                            const float* __restrict__ fc2_w,
                                            const float* __restrict__ fc2_b,
                                            float* __restrict__ out) {
    __shared__ float hv[32];
    __shared__ float lg[5];
    int tid = threadIdx.x;
    if (tid < 32) hv[tid] = eluf(h1[tid] + fc1_b[tid]);
    __syncthreads();
    if (tid < 5) {
        float s = fc2_b[tid];
        for (int j = 0; j < 32; j++) s = fmaf(hv[j], fc2_w[j * 5 + tid], s);
        lg[tid] = s;
    }
    __syncthreads();
    if (tid == 0) {
        float m = lg[0];
        for (int k = 1; k < 5; k++) m = fmaxf(m, lg[k]);
        float e[5], sum = 0.f;
        for (int k = 0; k < 5; k++) { e[k] = expf(lg[k] - m); sum += e[k]; }
        for (int k = 0; k < 5; k++) out[k] = e[k] / sum;
    }
}

extern "C" void kernel_launch(void* const* d_in, const int* in_sizes, int n_in,
                              void* d_out, int out_size, void* d_ws, size_t ws_size,
                              hipStream_t stream) {
    const int* coords = (const int*)d_in[0];
    const float* feats = (const float*)d_in[1];
    const float* w1 = (const float*)d_in[2];
    const float* w2 = (const float*)d_in[3];
    const float* w3 = (const float*)d_in[4];
    const float* w4 = (const float*)d_in[5];
    const float* fc1w = (const float*)d_in[6];
    const float* fc1b = (const float*)d_in[7];
    const float* fc2w = (const float*)d_in[8];
    const float* fc2b = (const float*)d_in[9];
    float* out = (float*)d_out;
    char* ws = (char*)d_ws;
    float* x0 = (float*)(ws + OFF_X0);
    unsigned* m0b = (unsigned*)(ws + OFF_M0B);
    float* y1 = (float*)(ws + OFF_Y1);
    unsigned char* m1g = (unsigned char*)(ws + OFF_M1);
    float* y2 = (float*)(ws + OFF_Y2);
    unsigned char* m2g = (unsigned char*)(ws + OFF_M2);
    float* y3 = (float*)(ws + OFF_Y3);
    unsigned char* m3g = (unsigned char*)(ws + OFF_M3);
    float* y4 = (float*)(ws + OFF_Y4);
    float* h1 = (float*)(ws + OFF_H1);
    float* p4 = (float*)(ws + OFF_P4);
    int P = in_sizes[1];

    // zero x0 + m0 bitfield (covers aliased y2..p4 regions too)
    hipMemsetAsync(ws, 0, OFF_Y1, stream);
    k_scatter<<<(P + 255) / 256, 256, 0, stream>>>(coords, feats, x0, m0b, P);
    k_l1<<<(S1 * S1) / 256, 256, 0, stream>>>(x0, m0b, w1, y1, m1g);
    k_l2<<<S2 * S2, 64, 0, stream>>>(y1, m1g, w2, y2, m2g);
    k_l3<<<S3 * S3, 256, 0, stream>>>(y2, m2g, w3, y3, m3g);
    k_l4<<<S4 * S4 * 5, 256, 0, stream>>>(y3, w4, p4);
    k_p4<<<S4 * S4, 256, 0, stream>>>(p4, m3g, y4);
    k_fc1<<<32, 256, 0, stream>>>(y4, fc1w, h1);
    k_fc2<<<1, 64, 0, stream>>>(h1, fc1b, fc2w, fc2b, out);
}

// Round 7
// 517.638 us; speedup vs baseline: 1.0294x; 1.0294x over previous
//
#include <hip/hip_runtime.h>
#include <math.h>

#define S0 3600
#define S1 720
#define S2 144
#define S3 36
#define S4 9
#define NEGF (-1e30f)

// ---- workspace layout (bytes). Peak 74.72 MB (proven in rounds 2-6).
static constexpr size_t OFF_X0  = 0;                                    // f32 [3600*3600] = 51,840,000
static constexpr size_t OFF_M0B = (size_t)S0 * S0 * 4;                  // u32 bitfield    = 1,620,000
static constexpr size_t OFF_Y1  = OFF_M0B + 1620000;                    // f32 [720*720*10] @53,460,000
static constexpr size_t OFF_M1  = OFF_Y1 + (size_t)S1 * S1 * 10 * 4;    // u8  [720*720]    @74,196,000 (ends 74,714,400)
// aliased into dead x0 region (used from conv2 onward):
static constexpr size_t OFF_Y2  = 0;                                    // f32 [144*144*64]  = 5,308,416
static constexpr size_t OFF_M2  = OFF_Y2 + (size_t)S2 * S2 * 64 * 4;    // u8  [144*144]
static constexpr size_t OFF_Y3  = OFF_M2 + 20736;                       // f32 [36*36*128] @5,329,152
static constexpr size_t OFF_M3  = OFF_Y3 + (size_t)S3 * S3 * 128 * 4;   // u8  [36*36]     @5,992,704
static constexpr size_t OFF_Y4  = OFF_M3 + 1296;                        // f32 [9*9*256]   @5,994,000
static constexpr size_t OFF_H1  = OFF_Y4 + (size_t)S4 * S4 * 256 * 4;   // f32 [32]        @6,076,944
static constexpr size_t OFF_P4  = 6077200;                              // f32 [81*5*16*256] = 6,635,520 (ends 12.7 MB)

__device__ __forceinline__ float eluf(float x) { return x > 0.f ? x : expm1f(x); }
__device__ __forceinline__ void fma4(float4& a, float s, const float4& w) {
    a.x = fmaf(s, w.x, a.x); a.y = fmaf(s, w.y, a.y);
    a.z = fmaf(s, w.z, a.z); a.w = fmaf(s, w.w, a.w);
}

// ---- scatter points onto dense grid -----------------------------------------
__global__ __launch_bounds__(256) void k_scatter(const int* __restrict__ coords,
                                                 const float* __restrict__ feats,
                                                 float* __restrict__ x0,
                                                 unsigned* __restrict__ m0b, int P) {
    int i = blockIdx.x * 256 + threadIdx.x;
    if (i >= P) return;
    int r = coords[2 * i], c = coords[2 * i + 1];
    int idx = r * S0 + c;
    atomicAdd(&x0[idx], feats[i]);
    atomicOr(&m0b[idx >> 5], 1u << (idx & 31));
}

// ---- layer 1: sparse conv 5x5 1->10 + ELU + maxpool5 (mask-bitfield-driven) -
__global__ __launch_bounds__(256) void k_l1(const float* __restrict__ x0,
                                            const unsigned* __restrict__ m0b,
                                            const float* __restrict__ w1,
                                            float* __restrict__ y1,
                                            unsigned char* __restrict__ m1) {
    __shared__ float w1s[250];
    int tid = threadIdx.x;
    if (tid < 250) w1s[tid] = w1[tid];
    __syncthreads();
    int t = blockIdx.x * 256 + tid;       // grid exact: 720*720 = 518400
    int pr = t / S1, pc = t % S1;
    int r0 = pr * 5 - 2, c0 = pc * 5 - 2; // 9x9 patch origin
    unsigned rows[9];
#pragma unroll
    for (int rr = 0; rr < 9; rr++) {
        unsigned bits = 0;
        int gr = r0 + rr;
        if (gr >= 0 && gr < S0) {
            int cs = c0 < 0 ? 0 : c0;
            int ce = c0 + 8 > S0 - 1 ? S0 - 1 : c0 + 8;
            int span = ce - cs;
            size_t i0 = (size_t)gr * S0 + cs;
            unsigned sh = (unsigned)(i0 & 31);
            unsigned long long two = (unsigned long long)m0b[i0 >> 5] >> sh;
            if ((int)sh + span >= 32)
                two |= (unsigned long long)m0b[(i0 >> 5) + 1] << (32 - sh);
            bits = (unsigned)(two & ((1u << (span + 1)) - 1));
            bits <<= (cs - c0);
        }
        rows[rr] = bits;
    }
    unsigned any25 = 0;
#pragma unroll
    for (int dy = 0; dy < 5; dy++) any25 |= (rows[2 + dy] >> 2) & 0x1Fu;
    float* yo = &y1[(size_t)t * 10];
    if (!any25) {
#pragma unroll
        for (int q = 0; q < 5; q++) ((float2*)yo)[q] = make_float2(0.f, 0.f);
        m1[t] = 0;
        return;
    }
    float2 mx[5];
#pragma unroll
    for (int q = 0; q < 5; q++) mx[q] = make_float2(NEGF, NEGF);
    for (int dy = 0; dy < 5; dy++) {
        unsigned crow = (rows[2 + dy] >> 2) & 0x1Fu;
        while (crow) {
            int dx = __ffs(crow) - 1; crow &= crow - 1;
            float2 acc[5];
#pragma unroll
            for (int q = 0; q < 5; q++) acc[q] = make_float2(0.f, 0.f);
#pragma unroll
            for (int ky = 0; ky < 5; ky++) {
                unsigned nrow = (rows[dy + ky] >> dx) & 0x1Fu;
                size_t rowbase = (size_t)(r0 + dy + ky) * S0 + (c0 + dx);
                while (nrow) {
                    int kx = __ffs(nrow) - 1; nrow &= nrow - 1;
                    float xv = x0[rowbase + kx];
                    const float2* wp = (const float2*)&w1s[(ky * 5 + kx) * 10];
#pragma unroll
                    for (int q = 0; q < 5; q++) {
                        float2 w = wp[q];
                        acc[q].x = fmaf(xv, w.x, acc[q].x);
                        acc[q].y = fmaf(xv, w.y, acc[q].y);
                    }
                }
            }
#pragma unroll
            for (int q = 0; q < 5; q++) {
                mx[q].x = fmaxf(mx[q].x, acc[q].x);
                mx[q].y = fmaxf(mx[q].y, acc[q].y);
            }
        }
    }
#pragma unroll
    for (int q = 0; q < 5; q++) {
        float2 o;
        o.x = eluf(mx[q].x); o.y = eluf(mx[q].y);
        ((float2*)yo)[q] = o;
    }
    m1[t] = 1;
}

// ---- layer 2: fused conv 5x5 10->64 (cell-gated) + ELU + maxpool5 -----------
__global__ __launch_bounds__(64) void k_l2(const float* __restrict__ y1,
                                           const unsigned char* __restrict__ m1,
                                           const float* __restrict__ w2,
                                           float* __restrict__ y2,
                                           unsigned char* __restrict__ m2) {
    __shared__ float win[81 * 12];
    __shared__ unsigned char sm[81];
    int b = blockIdx.x;
    int pr = b / S2, pc = b % S2;
    int r0 = pr * 5 - 2, c0 = pc * 5 - 2;
    int tid = threadIdx.x;
    for (int k = tid; k < 81; k += 64) {
        int gr = r0 + k / 9, gc = c0 + k % 9;
        bool ok = (gr >= 0 && gr < S1 && gc >= 0 && gc < S1);
        sm[k] = ok ? m1[gr * S1 + gc] : (unsigned char)0;
        float* dst = &win[k * 12];
        if (ok) {
            const float2* src = (const float2*)&y1[((size_t)gr * S1 + gc) * 10];
#pragma unroll
            for (int q = 0; q < 5; q++) ((float2*)dst)[q] = src[q];
        } else {
#pragma unroll
            for (int q = 0; q < 5; q++) ((float2*)dst)[q] = make_float2(0.f, 0.f);
        }
        dst[10] = 0.f; dst[11] = 0.f;
    }
    __syncthreads();
    int c = tid;
    unsigned mbits = 0;
#pragma unroll
    for (int cell = 0; cell < 25; cell++) {
        if (sm[(2 + cell / 5) * 9 + (2 + cell % 5)]) mbits |= (1u << cell);
    }
    mbits = (unsigned)__builtin_amdgcn_readfirstlane((int)mbits);
    float acc[25];
#pragma unroll
    for (int i = 0; i < 25; i++) acc[i] = 0.f;
    for (int t5 = 0; t5 < 25; t5++) {
        float w[10];
#pragma unroll
        for (int ci = 0; ci < 10; ci++) w[ci] = w2[(t5 * 10 + ci) * 64 + c];
        int base = (t5 / 5) * 9 + (t5 % 5);
#pragma unroll
        for (int cell = 0; cell < 25; cell++) {
            if (mbits & (1u << cell)) {
                const float4* xp = (const float4*)&win[(base + (cell / 5) * 9 + (cell % 5)) * 12];
                float4 xa = xp[0], xb = xp[1], xc = xp[2];
                float a = acc[cell];
                a = fmaf(xa.x, w[0], a); a = fmaf(xa.y, w[1], a);
                a = fmaf(xa.z, w[2], a); a = fmaf(xa.w, w[3], a);
                a = fmaf(xb.x, w[4], a); a = fmaf(xb.y, w[5], a);
                a = fmaf(xb.z, w[6], a); a = fmaf(xb.w, w[7], a);
                a = fmaf(xc.x, w[8], a); a = fmaf(xc.y, w[9], a);
                acc[cell] = a;
            }
        }
    }
    float mx = NEGF;
#pragma unroll
    for (int cell = 0; cell < 25; cell++)
        if (mbits & (1u << cell)) mx = fmaxf(mx, acc[cell]);
    bool any = (mbits != 0);
    y2[((size_t)pr * S2 + pc) * 64 + c] = any ? eluf(mx) : 0.f;
    if (c == 0) m2[pr * S2 + pc] = any ? 1 : 0;
}

// ---- layer 3: fused conv 5x5 64->128 + ELU + maxpool4 -> 36^2 ---------------
// 256 thr/block; thread = (co-pair 0..63, K-quarter 0..3): 16 cells x 2 co.
// Weight loads: 4 dwordx2/step (512 B/wave-instr coalesced, TCP-light).
// x loads: 16 ds_read_b128/step with ALL 64 lanes at the same address
// (pure LDS broadcast, free). K-quarter partials summed via LDS.
__global__ __launch_bounds__(256) void k_l3(const float* __restrict__ y2,
                                            const unsigned char* __restrict__ m2,
                                            const float* __restrict__ w3,
                                            float* __restrict__ y3,
                                            unsigned char* __restrict__ m3) {
    __shared__ float win[8 * 8 * 64];    // 16 KB, [cell(r*8+c)][ci]
    __shared__ float part[4][16][128];   // 32 KB, [kq][cell][co]
    __shared__ unsigned char sm[16];
    int b = blockIdx.x;                  // 0..1295
    int ppr = b / S3, ppc = b % S3;
    int r0 = ppr * 4 - 2, c0 = ppc * 4 - 2;
    int tid = threadIdx.x;
    float4* win4 = (float4*)win;
    for (int k = tid; k < 1024; k += 256) {
        int cellk = k >> 4, q = k & 15;
        int gr = r0 + (cellk >> 3), gc = c0 + (cellk & 7);
        float4 v = make_float4(0.f, 0.f, 0.f, 0.f);
        if (gr >= 0 && gr < S2 && gc >= 0 && gc < S2)
            v = ((const float4*)y2)[((size_t)gr * S2 + gc) * 16 + q];
        win4[k] = v;
    }
    if (tid < 16) sm[tid] = m2[(ppr * 4 + (tid >> 2)) * S2 + ppc * 4 + (tid & 3)];
    __syncthreads();
    int cp = tid & 63;                   // co-pair -> co = cp*2, cp*2+1
    int kq = tid >> 6;                   // ci-quarter 0..3 (ci in [kq*16, kq*16+16))
    float2 acc[16];
#pragma unroll
    for (int i = 0; i < 16; i++) acc[i] = make_float2(0.f, 0.f);
#pragma unroll 1
    for (int t5 = 0; t5 < 25; t5++) {
        int ky = t5 / 5, kx = t5 % 5;
        const float* wb = &w3[(size_t)(t5 * 64 + kq * 16) * 128 + cp * 2];
        int xbase = (ky * 8 + kx) * 16 + kq * 4;   // + cell offset + j
#pragma unroll
        for (int j = 0; j < 4; j++) {
            float2 w0 = *(const float2*)&wb[(j * 4 + 0) * 128];
            float2 w1 = *(const float2*)&wb[(j * 4 + 1) * 128];
            float2 w2v = *(const float2*)&wb[(j * 4 + 2) * 128];
            float2 w3v = *(const float2*)&wb[(j * 4 + 3) * 128];
#pragma unroll
            for (int cell = 0; cell < 16; cell++) {
                float4 xv = win4[xbase + ((cell >> 2) * 8 + (cell & 3)) * 16 + j];
                float2 a = acc[cell];
                a.x = fmaf(xv.x, w0.x, a.x); a.y = fmaf(xv.x, w0.y, a.y);
                a.x = fmaf(xv.y, w1.x, a.x); a.y = fmaf(xv.y, w1.y, a.y);
                a.x = fmaf(xv.z, w2v.x, a.x); a.y = fmaf(xv.z, w2v.y, a.y);
                a.x = fmaf(xv.w, w3v.x, a.x); a.y = fmaf(xv.w, w3v.y, a.y);
                acc[cell] = a;
            }
        }
    }
#pragma unroll
    for (int cell = 0; cell < 16; cell++)
        *(float2*)&part[kq][cell][cp * 2] = acc[cell];
    __syncthreads();
    bool any = false;
#pragma unroll
    for (int i = 0; i < 16; i++) any |= (sm[i] != 0);
    if (tid < 128) {
        int co = tid;
        float m = NEGF;
#pragma unroll
        for (int cell = 0; cell < 16; cell++) {
            if (sm[cell]) {
                float v = part[0][cell][co] + part[1][cell][co]
                        + part[2][cell][co] + part[3][cell][co];
                m = fmaxf(m, v);
            }
        }
        y3[(size_t)b * 128 + co] = any ? eluf(m) : 0.f;
    }
    if (tid == 0) m3[b] = any ? 1 : 0;
}

// ---- layer 4 conv, K-split over ky: block = (pool cell, ky) -----------------
__global__ __launch_bounds__(256) void k_l4(const float* __restrict__ y3,
                                            const float* __restrict__ w4,
                                            float* __restrict__ part) {
    __shared__ float win[4 * 8 * 128];  // 16 KB
    int b = blockIdx.x;                  // 0..404
    int p = b / 5, ky = b % 5;
    int ppr = p / S4, ppc = p % S4;
    int r0 = ppr * 4 - 2 + ky, c0 = ppc * 4 - 2;
    int tid = threadIdx.x;
    float4* win4 = (float4*)win;
    for (int k = tid; k < 1024; k += 256) {
        int cellk = k >> 5, q = k & 31;  // cellk = rr*8+cc, rr 0..3
        int gr = r0 + (cellk >> 3), gc = c0 + (cellk & 7);
        float4 v = make_float4(0.f, 0.f, 0.f, 0.f);
        if (gr >= 0 && gr < S3 && gc >= 0 && gc < S3)
            v = ((const float4*)y3)[((size_t)gr * S3 + gc) * 32 + q];
        win4[k] = v;
    }
    __syncthreads();
    int cq = tid & 63, pr = tid >> 6;    // co-quad 0..63, cell-row 0..3
    int co4 = cq * 4;
    float4 acc[4];
#pragma unroll
    for (int i = 0; i < 4; i++) acc[i] = make_float4(0.f, 0.f, 0.f, 0.f);
#pragma unroll 1
    for (int kx = 0; kx < 5; kx++) {
        int rowbase = pr * 8 + kx;                           // + pc
        const float4* wq = (const float4*)&w4[(size_t)((ky * 5 + kx) * 128) * 256 + co4];
#pragma unroll 4
        for (int ci4 = 0; ci4 < 32; ci4++) {
            float4 xv0 = win4[(rowbase + 0) * 32 + ci4];
            float4 xv1 = win4[(rowbase + 1) * 32 + ci4];
            float4 xv2 = win4[(rowbase + 2) * 32 + ci4];
            float4 xv3 = win4[(rowbase + 3) * 32 + ci4];
            float4 w0 = wq[(ci4 * 4 + 0) * 64];
            float4 w1 = wq[(ci4 * 4 + 1) * 64];
            float4 w2v = wq[(ci4 * 4 + 2) * 64];
            float4 w3v = wq[(ci4 * 4 + 3) * 64];
            fma4(acc[0], xv0.x, w0); fma4(acc[0], xv0.y, w1); fma4(acc[0], xv0.z, w2v); fma4(acc[0], xv0.w, w3v);
            fma4(acc[1], xv1.x, w0); fma4(acc[1], xv1.y, w1); fma4(acc[1], xv1.z, w2v); fma4(acc[1], xv1.w, w3v);
            fma4(acc[2], xv2.x, w0); fma4(acc[2], xv2.y, w1); fma4(acc[2], xv2.z, w2v); fma4(acc[2], xv2.w, w3v);
            fma4(acc[3], xv3.x, w0); fma4(acc[3], xv3.y, w1); fma4(acc[3], xv3.z, w2v); fma4(acc[3], xv3.w, w3v);
        }
    }
#pragma unroll
    for (int pc = 0; pc < 4; pc++) {
        int cell = pr * 4 + pc;
        *(float4*)&part[(((size_t)p * 5 + ky) * 16 + cell) * 256 + co4] = acc[pc];
    }
}

// ---- layer 4 reduce K-partials + ELU + maxpool4 -> 9^2 ----------------------
__global__ __launch_bounds__(256) void k_p4(const float* __restrict__ part,
                                            const unsigned char* __restrict__ m3,
                                            float* __restrict__ y4) {
    int p = blockIdx.x;                  // 0..80
    int co = threadIdx.x;                // 0..255
    int ppr = p / S4, ppc = p % S4;
    float mx = NEGF;
    bool any = false;
    for (int cell = 0; cell < 16; cell++) {
        int site = (ppr * 4 + (cell >> 2)) * S3 + ppc * 4 + (cell & 3);
        if (!m3[site]) continue;
        any = true;
        float s = 0.f;
#pragma unroll
        for (int ky = 0; ky < 5; ky++)
            s += part[(((size_t)p * 5 + ky) * 16 + cell) * 256 + co];
        mx = fmaxf(mx, s);
    }
    y4[(size_t)p * 256 + co] = any ? eluf(mx) : 0.f;
}

// ---- fc1 (deterministic): 32 blocks, block j computes h1[j] -----------------
__global__ __launch_bounds__(256) void k_fc1(const float* __restrict__ y4,
                                             const float* __restrict__ fc1_w,
                                             float* __restrict__ h1) {
    __shared__ float part[256];
    int j = blockIdx.x;                    // 0..31
    int tid = threadIdx.x;
    float s = 0.f;
    for (int i = tid; i < 256 * 81; i += 256) {
        int c = i / 81, rem = i % 81;      // NCHW flatten: i = c*81 + h*9 + w
        s = fmaf(y4[(size_t)rem * 256 + c], fc1_w[(size_t)i * 32 + j], s);
    }
    part[tid] = s;
    __syncthreads();
    for (int off = 128; off > 0; off >>= 1) {
        if (tid < off) part[tid] += part[tid + off];
        __syncthreads();
    }
    if (tid == 0) h1[j] = part[0];
}

// ---- fc2 + softmax ----------------------------------------------------------
__global__ __launch_bounds__(64) void k_fc2(const float* __restrict__ h1,
                                            const float* __restrict__ fc1_b,
                                            const float* __restrict__ fc2_w,
                                            const float* __restrict__ fc2_b,
                                            float* __restrict__ out) {
    __shared__ float hv[32];
    __shared__ float lg[5];
    int tid = threadIdx.x;
    if (tid < 32) hv[tid] = eluf(h1[tid] + fc1_b[tid]);
    __syncthreads();
    if (tid < 5) {
        float s = fc2_b[tid];
        for (int j = 0; j < 32; j++) s = fmaf(hv[j], fc2_w[j * 5 + tid], s);
        lg[tid] = s;
    }
    __syncthreads();
    if (tid == 0) {
        float m = lg[0];
        for (int k = 1; k < 5; k++) m = fmaxf(m, lg[k]);
        float e[5], sum = 0.f;
        for (int k = 0; k < 5; k++) { e[k] = expf(lg[k] - m); sum += e[k]; }
        for (int k = 0; k < 5; k++) out[k] = e[k] / sum;
    }
}

extern "C" void kernel_launch(void* const* d_in, const int* in_sizes, int n_in,
                              void* d_out, int out_size, void* d_ws, size_t ws_size,
                              hipStream_t stream) {
    const int* coords = (const int*)d_in[0];
    const float* feats = (const float*)d_in[1];
    const float* w1 = (const float*)d_in[2];
    const float* w2 = (const float*)d_in[3];
    const float* w3 = (const float*)d_in[4];
    const float* w4 = (const float*)d_in[5];
    const float* fc1w = (const float*)d_in[6];
    const float* fc1b = (const float*)d_in[7];
    const float* fc2w = (const float*)d_in[8];
    const float* fc2b = (const float*)d_in[9];
    float* out = (float*)d_out;
    char* ws = (char*)d_ws;
    float* x0 = (float*)(ws + OFF_X0);
    unsigned* m0b = (unsigned*)(ws + OFF_M0B);
    float* y1 = (float*)(ws + OFF_Y1);
    unsigned char* m1g = (unsigned char*)(ws + OFF_M1);
    float* y2 = (float*)(ws + OFF_Y2);
    unsigned char* m2g = (unsigned char*)(ws + OFF_M2);
    float* y3 = (float*)(ws + OFF_Y3);
    unsigned char* m3g = (unsigned char*)(ws + OFF_M3);
    float* y4 = (float*)(ws + OFF_Y4);
    float* h1 = (float*)(ws + OFF_H1);
    float* p4 = (float*)(ws + OFF_P4);
    int P = in_sizes[1];

    // zero x0 + m0 bitfield (covers aliased y2..p4 regions too)
    hipMemsetAsync(ws, 0, OFF_Y1, stream);
    k_scatter<<<(P + 255) / 256, 256, 0, stream>>>(coords, feats, x0, m0b, P);
    k_l1<<<(S1 * S1) / 256, 256, 0, stream>>>(x0, m0b, w1, y1, m1g);
    k_l2<<<S2 * S2, 64, 0, stream>>>(y1, m1g, w2, y2, m2g);
    k_l3<<<S3 * S3, 256, 0, stream>>>(y2, m2g, w3, y3, m3g);
    k_l4<<<S4 * S4 * 5, 256, 0, stream>>>(y3, w4, p4);
    k_p4<<<S4 * S4, 256, 0, stream>>>(p4, m3g, y4);
    k_fc1<<<32, 256, 0, stream>>>(y4, fc1w, h1);
    k_fc2<<<1, 64, 0, stream>>>(h1, fc1b, fc2w, fc2b, out);
}

// Round 9
// 510.026 us; speedup vs baseline: 1.0448x; 1.0149x over previous
//
#include <hip/hip_runtime.h>
#include <math.h>

#define S0 3600
#define S1 720
#define S2 144
#define S3 36
#define S4 9
#define NEGF (-1e30f)

// ---- workspace layout (bytes). Peak 74.72 MB (proven in rounds 2-7).
static constexpr size_t OFF_X0  = 0;                                    // f32 [3600*3600] = 51,840,000
static constexpr size_t OFF_M0B = (size_t)S0 * S0 * 4;                  // u32 bitfield    = 1,620,000
static constexpr size_t OFF_Y1  = OFF_M0B + 1620000;                    // f32 [720*720*10] @53,460,000
static constexpr size_t OFF_M1  = OFF_Y1 + (size_t)S1 * S1 * 10 * 4;    // u8  [720*720]    @74,196,000 (ends 74,714,400)
// aliased into dead x0 region (used from conv2 onward):
static constexpr size_t OFF_Y2  = 0;                                    // f32 [144*144*64]  = 5,308,416
static constexpr size_t OFF_M2  = OFF_Y2 + (size_t)S2 * S2 * 64 * 4;    // u8  [144*144]
static constexpr size_t OFF_Y3  = OFF_M2 + 20736;                       // f32 [36*36*128] @5,329,152
static constexpr size_t OFF_M3  = OFF_Y3 + (size_t)S3 * S3 * 128 * 4;   // u8  [36*36]     @5,992,704
static constexpr size_t OFF_Y4  = OFF_M3 + 1296;                        // f32 [9*9*256]   @5,994,000
static constexpr size_t OFF_H1  = OFF_Y4 + (size_t)S4 * S4 * 256 * 4;   // f32 [32]        @6,076,944
static constexpr size_t OFF_P4  = 6077200;                              // f32 [81*5*16*256] = 6,635,520 (ends 12.7 MB)

__device__ __forceinline__ float eluf(float x) { return x > 0.f ? x : expm1f(x); }
__device__ __forceinline__ void fma4(float4& a, float s, const float4& w) {
    a.x = fmaf(s, w.x, a.x); a.y = fmaf(s, w.y, a.y);
    a.z = fmaf(s, w.z, a.z); a.w = fmaf(s, w.w, a.w);
}

// ---- scatter points onto dense grid -----------------------------------------
__global__ __launch_bounds__(256) void k_scatter(const int* __restrict__ coords,
                                                 const float* __restrict__ feats,
                                                 float* __restrict__ x0,
                                                 unsigned* __restrict__ m0b, int P) {
    int i = blockIdx.x * 256 + threadIdx.x;
    if (i >= P) return;
    int r = coords[2 * i], c = coords[2 * i + 1];
    int idx = r * S0 + c;
    atomicAdd(&x0[idx], feats[i]);
    atomicOr(&m0b[idx >> 5], 1u << (idx & 31));
}

// ---- layer 1: sparse conv 5x5 1->10 + ELU + maxpool5 (mask-bitfield-driven) -
__global__ __launch_bounds__(256) void k_l1(const float* __restrict__ x0,
                                            const unsigned* __restrict__ m0b,
                                            const float* __restrict__ w1,
                                            float* __restrict__ y1,
                                            unsigned char* __restrict__ m1) {
    __shared__ float w1s[250];
    int tid = threadIdx.x;
    if (tid < 250) w1s[tid] = w1[tid];
    __syncthreads();
    int t = blockIdx.x * 256 + tid;       // grid exact: 720*720 = 518400
    int pr = t / S1, pc = t % S1;
    int r0 = pr * 5 - 2, c0 = pc * 5 - 2; // 9x9 patch origin
    unsigned rows[9];
#pragma unroll
    for (int rr = 0; rr < 9; rr++) {
        unsigned bits = 0;
        int gr = r0 + rr;
        if (gr >= 0 && gr < S0) {
            int cs = c0 < 0 ? 0 : c0;
            int ce = c0 + 8 > S0 - 1 ? S0 - 1 : c0 + 8;
            int span = ce - cs;
            size_t i0 = (size_t)gr * S0 + cs;
            unsigned sh = (unsigned)(i0 & 31);
            unsigned long long two = (unsigned long long)m0b[i0 >> 5] >> sh;
            if ((int)sh + span >= 32)
                two |= (unsigned long long)m0b[(i0 >> 5) + 1] << (32 - sh);
            bits = (unsigned)(two & ((1u << (span + 1)) - 1));
            bits <<= (cs - c0);
        }
        rows[rr] = bits;
    }
    unsigned any25 = 0;
#pragma unroll
    for (int dy = 0; dy < 5; dy++) any25 |= (rows[2 + dy] >> 2) & 0x1Fu;
    float* yo = &y1[(size_t)t * 10];
    if (!any25) {
#pragma unroll
        for (int q = 0; q < 5; q++) ((float2*)yo)[q] = make_float2(0.f, 0.f);
        m1[t] = 0;
        return;
    }
    float2 mx[5];
#pragma unroll
    for (int q = 0; q < 5; q++) mx[q] = make_float2(NEGF, NEGF);
    for (int dy = 0; dy < 5; dy++) {
        unsigned crow = (rows[2 + dy] >> 2) & 0x1Fu;
        while (crow) {
            int dx = __ffs(crow) - 1; crow &= crow - 1;
            float2 acc[5];
#pragma unroll
            for (int q = 0; q < 5; q++) acc[q] = make_float2(0.f, 0.f);
#pragma unroll
            for (int ky = 0; ky < 5; ky++) {
                unsigned nrow = (rows[dy + ky] >> dx) & 0x1Fu;
                size_t rowbase = (size_t)(r0 + dy + ky) * S0 + (c0 + dx);
                while (nrow) {
                    int kx = __ffs(nrow) - 1; nrow &= nrow - 1;
                    float xv = x0[rowbase + kx];
                    const float2* wp = (const float2*)&w1s[(ky * 5 + kx) * 10];
#pragma unroll
                    for (int q = 0; q < 5; q++) {
                        float2 w = wp[q];
                        acc[q].x = fmaf(xv, w.x, acc[q].x);
                        acc[q].y = fmaf(xv, w.y, acc[q].y);
                    }
                }
            }
#pragma unroll
            for (int q = 0; q < 5; q++) {
                mx[q].x = fmaxf(mx[q].x, acc[q].x);
                mx[q].y = fmaxf(mx[q].y, acc[q].y);
            }
        }
    }
#pragma unroll
    for (int q = 0; q < 5; q++) {
        float2 o;
        o.x = eluf(mx[q].x); o.y = eluf(mx[q].y);
        ((float2*)yo)[q] = o;
    }
    m1[t] = 1;
}

// ---- layer 2: fused conv 5x5 10->64 (cell-gated) + ELU + maxpool5 -----------
__global__ __launch_bounds__(64) void k_l2(const float* __restrict__ y1,
                                           const unsigned char* __restrict__ m1,
                                           const float* __restrict__ w2,
                                           float* __restrict__ y2,
                                           unsigned char* __restrict__ m2) {
    __shared__ float win[81 * 12];
    __shared__ unsigned char sm[81];
    int b = blockIdx.x;
    int pr = b / S2, pc = b % S2;
    int r0 = pr * 5 - 2, c0 = pc * 5 - 2;
    int tid = threadIdx.x;
    for (int k = tid; k < 81; k += 64) {
        int gr = r0 + k / 9, gc = c0 + k % 9;
        bool ok = (gr >= 0 && gr < S1 && gc >= 0 && gc < S1);
        sm[k] = ok ? m1[gr * S1 + gc] : (unsigned char)0;
        float* dst = &win[k * 12];
        if (ok) {
            const float2* src = (const float2*)&y1[((size_t)gr * S1 + gc) * 10];
#pragma unroll
            for (int q = 0; q < 5; q++) ((float2*)dst)[q] = src[q];
        } else {
#pragma unroll
            for (int q = 0; q < 5; q++) ((float2*)dst)[q] = make_float2(0.f, 0.f);
        }
        dst[10] = 0.f; dst[11] = 0.f;
    }
    __syncthreads();
    int c = tid;
    unsigned mbits = 0;
#pragma unroll
    for (int cell = 0; cell < 25; cell++) {
        if (sm[(2 + cell / 5) * 9 + (2 + cell % 5)]) mbits |= (1u << cell);
    }
    mbits = (unsigned)__builtin_amdgcn_readfirstlane((int)mbits);
    float acc[25];
#pragma unroll
    for (int i = 0; i < 25; i++) acc[i] = 0.f;
    for (int t5 = 0; t5 < 25; t5++) {
        float w[10];
#pragma unroll
        for (int ci = 0; ci < 10; ci++) w[ci] = w2[(t5 * 10 + ci) * 64 + c];
        int base = (t5 / 5) * 9 + (t5 % 5);
#pragma unroll
        for (int cell = 0; cell < 25; cell++) {
            if (mbits & (1u << cell)) {
                const float4* xp = (const float4*)&win[(base + (cell / 5) * 9 + (cell % 5)) * 12];
                float4 xa = xp[0], xb = xp[1], xc = xp[2];
                float a = acc[cell];
                a = fmaf(xa.x, w[0], a); a = fmaf(xa.y, w[1], a);
                a = fmaf(xa.z, w[2], a); a = fmaf(xa.w, w[3], a);
                a = fmaf(xb.x, w[4], a); a = fmaf(xb.y, w[5], a);
                a = fmaf(xb.z, w[6], a); a = fmaf(xb.w, w[7], a);
                a = fmaf(xc.x, w[8], a); a = fmaf(xc.y, w[9], a);
                acc[cell] = a;
            }
        }
    }
    float mx = NEGF;
#pragma unroll
    for (int cell = 0; cell < 25; cell++)
        if (mbits & (1u << cell)) mx = fmaxf(mx, acc[cell]);
    bool any = (mbits != 0);
    y2[((size_t)pr * S2 + pc) * 64 + c] = any ? eluf(mx) : 0.f;
    if (c == 0) m2[pr * S2 + pc] = any ? 1 : 0;
}

// ---- layer 3: fused conv 5x5 64->128 + ELU + maxpool4 -> 36^2 ---------------
// 128 thr/block; thread = (co-quad 0..31 -> 4 co, K-quarter 0..3 -> 16 ci).
// Tile M=16 cells x N=4 co: per inner step 4 coalesced dwordx4 w-loads +
// 16 LDS b128 x-reads feed 256 FMAs (1.25 operand-bytes/FMA -> LDS pipe
// no longer oversubscribed). kq-partials summed via LDS (order == round 7).
__global__ __launch_bounds__(128) void k_l3(const float* __restrict__ y2,
                                            const unsigned char* __restrict__ m2,
                                            const float* __restrict__ w3,
                                            float* __restrict__ y3,
                                            unsigned char* __restrict__ m3) {
    __shared__ float win[8 * 8 * 64];    // 16 KB, [cell(r*8+c)][ci]
    __shared__ float part[4][16][128];   // 32 KB, [kq][cell][co]
    __shared__ unsigned char sm[16];
    int b = blockIdx.x;                  // 0..1295
    int ppr = b / S3, ppc = b % S3;
    int r0 = ppr * 4 - 2, c0 = ppc * 4 - 2;
    int tid = threadIdx.x;
    float4* win4 = (float4*)win;
    for (int k = tid; k < 1024; k += 128) {
        int cellk = k >> 4, q = k & 15;
        int gr = r0 + (cellk >> 3), gc = c0 + (cellk & 7);
        float4 v = make_float4(0.f, 0.f, 0.f, 0.f);
        if (gr >= 0 && gr < S2 && gc >= 0 && gc < S2)
            v = ((const float4*)y2)[((size_t)gr * S2 + gc) * 16 + q];
        win4[k] = v;
    }
    if (tid < 16) sm[tid] = m2[(ppr * 4 + (tid >> 2)) * S2 + ppc * 4 + (tid & 3)];
    __syncthreads();
    int cog = tid & 31;                  // co = cog*4 .. +3
    int kq = tid >> 5;                   // ci-quarter 0..3 (ci in [kq*16, kq*16+16))
    float4 acc[16];
#pragma unroll
    for (int i = 0; i < 16; i++) acc[i] = make_float4(0.f, 0.f, 0.f, 0.f);
#pragma unroll 1
    for (int t5 = 0; t5 < 25; t5++) {
        int ky = t5 / 5, kx = t5 % 5;
        const float4* wb = (const float4*)&w3[(size_t)(t5 * 64 + kq * 16) * 128 + cog * 4];
        int xbase = (ky * 8 + kx) * 16 + kq * 4;   // + j
#pragma unroll
        for (int j = 0; j < 4; j++) {
            float4 w0 = wb[(j * 4 + 0) * 32];
            float4 w1 = wb[(j * 4 + 1) * 32];
            float4 w2v = wb[(j * 4 + 2) * 32];
            float4 w3v = wb[(j * 4 + 3) * 32];
            int xb = xbase + j;
#pragma unroll
            for (int cell = 0; cell < 16; cell++) {
                float4 xv = win4[xb + ((cell >> 2) * 8 + (cell & 3)) * 16];
                fma4(acc[cell], xv.x, w0);
                fma4(acc[cell], xv.y, w1);
                fma4(acc[cell], xv.z, w2v);
                fma4(acc[cell], xv.w, w3v);
            }
        }
    }
#pragma unroll
    for (int cell = 0; cell < 16; cell++)
        *(float4*)&part[kq][cell][cog * 4] = acc[cell];
    __syncthreads();
    bool any = false;
#pragma unroll
    for (int i = 0; i < 16; i++) any |= (sm[i] != 0);
    {
        int co = tid;                    // 0..127 covers all out channels
        float m = NEGF;
#pragma unroll
        for (int cell = 0; cell < 16; cell++) {
            if (sm[cell]) {
                float v = part[0][cell][co] + part[1][cell][co]
                        + part[2][cell][co] + part[3][cell][co];
                m = fmaxf(m, v);
            }
        }
        y3[(size_t)b * 128 + co] = any ? eluf(m) : 0.f;
    }
    if (tid == 0) m3[b] = any ? 1 : 0;
}

// ---- layer 4 conv, K-split over ky: block = (pool cell, ky) -----------------
__global__ __launch_bounds__(256) void k_l4(const float* __restrict__ y3,
                                            const float* __restrict__ w4,
                                            float* __restrict__ part) {
    __shared__ float win[4 * 8 * 128];  // 16 KB
    int b = blockIdx.x;                  // 0..404
    int p = b / 5, ky = b % 5;
    int ppr = p / S4, ppc = p % S4;
    int r0 = ppr * 4 - 2 + ky, c0 = ppc * 4 - 2;
    int tid = threadIdx.x;
    float4* win4 = (float4*)win;
    for (int k = tid; k < 1024; k += 256) {
        int cellk = k >> 5, q = k & 31;  // cellk = rr*8+cc, rr 0..3
        int gr = r0 + (cellk >> 3), gc = c0 + (cellk & 7);
        float4 v = make_float4(0.f, 0.f, 0.f, 0.f);
        if (gr >= 0 && gr < S3 && gc >= 0 && gc < S3)
            v = ((const float4*)y3)[((size_t)gr * S3 + gc) * 32 + q];
        win4[k] = v;
    }
    __syncthreads();
    int cq = tid & 63, pr = tid >> 6;    // co-quad 0..63, cell-row 0..3
    int co4 = cq * 4;
    float4 acc[4];
#pragma unroll
    for (int i = 0; i < 4; i++) acc[i] = make_float4(0.f, 0.f, 0.f, 0.f);
#pragma unroll 1
    for (int kx = 0; kx < 5; kx++) {
        int rowbase = pr * 8 + kx;                           // + pc
        const float4* wq = (const float4*)&w4[(size_t)((ky * 5 + kx) * 128) * 256 + co4];
#pragma unroll 4
        for (int ci4 = 0; ci4 < 32; ci4++) {
            float4 xv0 = win4[(rowbase + 0) * 32 + ci4];
            float4 xv1 = win4[(rowbase + 1) * 32 + ci4];
            float4 xv2 = win4[(rowbase + 2) * 32 + ci4];
            float4 xv3 = win4[(rowbase + 3) * 32 + ci4];
            float4 w0 = wq[(ci4 * 4 + 0) * 64];
            float4 w1 = wq[(ci4 * 4 + 1) * 64];
            float4 w2v = wq[(ci4 * 4 + 2) * 64];
            float4 w3v = wq[(ci4 * 4 + 3) * 64];
            fma4(acc[0], xv0.x, w0); fma4(acc[0], xv0.y, w1); fma4(acc[0], xv0.z, w2v); fma4(acc[0], xv0.w, w3v);
            fma4(acc[1], xv1.x, w0); fma4(acc[1], xv1.y, w1); fma4(acc[1], xv1.z, w2v); fma4(acc[1], xv1.w, w3v);
            fma4(acc[2], xv2.x, w0); fma4(acc[2], xv2.y, w1); fma4(acc[2], xv2.z, w2v); fma4(acc[2], xv2.w, w3v);
            fma4(acc[3], xv3.x, w0); fma4(acc[3], xv3.y, w1); fma4(acc[3], xv3.z, w2v); fma4(acc[3], xv3.w, w3v);
        }
    }
#pragma unroll
    for (int pc = 0; pc < 4; pc++) {
        int cell = pr * 4 + pc;
        *(float4*)&part[(((size_t)p * 5 + ky) * 16 + cell) * 256 + co4] = acc[pc];
    }
}

// ---- layer 4 reduce K-partials + ELU + maxpool4 -> 9^2 ----------------------
__global__ __launch_bounds__(256) void k_p4(const float* __restrict__ part,
                                            const unsigned char* __restrict__ m3,
                                            float* __restrict__ y4) {
    int p = blockIdx.x;                  // 0..80
    int co = threadIdx.x;                // 0..255
    int ppr = p / S4, ppc = p % S4;
    float mx = NEGF;
    bool any = false;
    for (int cell = 0; cell < 16; cell++) {
        int site = (ppr * 4 + (cell >> 2)) * S3 + ppc * 4 + (cell & 3);
        if (!m3[site]) continue;
        any = true;
        float s = 0.f;
#pragma unroll
        for (int ky = 0; ky < 5; ky++)
            s += part[(((size_t)p * 5 + ky) * 16 + cell) * 256 + co];
        mx = fmaxf(mx, s);
    }
    y4[(size_t)p * 256 + co] = any ? eluf(mx) : 0.f;
}

// ---- fc1 (deterministic): 32 blocks, block j computes h1[j] -----------------
__global__ __launch_bounds__(256) void k_fc1(const float* __restrict__ y4,
                                             const float* __restrict__ fc1_w,
                                             float* __restrict__ h1) {
    __shared__ float part[256];
    int j = blockIdx.x;                    // 0..31
    int tid = threadIdx.x;
    float s = 0.f;
    for (int i = tid; i < 256 * 81; i += 256) {
        int c = i / 81, rem = i % 81;      // NCHW flatten: i = c*81 + h*9 + w
        s = fmaf(y4[(size_t)rem * 256 + c], fc1_w[(size_t)i * 32 + j], s);
    }
    part[tid] = s;
    __syncthreads();
    for (int off = 128; off > 0; off >>= 1) {
        if (tid < off) part[tid] += part[tid + off];
        __syncthreads();
    }
    if (tid == 0) h1[j] = part[0];
}

// ---- fc2 + softmax ----------------------------------------------------------
__global__ __launch_bounds__(64) void k_fc2(const float* __restrict__ h1,
                                            const float* __restrict__ fc1_b,
                                            const float* __restrict__ fc2_w,
                                            const float* __restrict__ fc2_b,
                                            float* __restrict__ out) {
    __shared__ float hv[32];
    __shared__ float lg[5];
    int tid = threadIdx.x;
    if (tid < 32) hv[tid] = eluf(h1[tid] + fc1_b[tid]);
    __syncthreads();
    if (tid < 5) {
        float s = fc2_b[tid];
        for (int j = 0; j < 32; j++) s = fmaf(hv[j], fc2_w[j * 5 + tid], s);
        lg[tid] = s;
    }
    __syncthreads();
    if (tid == 0) {
        float m = lg[0];
        for (int k = 1; k < 5; k++) m = fmaxf(m, lg[k]);
        float e[5], sum = 0.f;
        for (int k = 0; k < 5; k++) { e[k] = expf(lg[k] - m); sum += e[k]; }
        for (int k = 0; k < 5; k++) out[k] = e[k] / sum;
    }
}

extern "C" void kernel_launch(void* const* d_in, const int* in_sizes, int n_in,
                              void* d_out, int out_size, void* d_ws, size_t ws_size,
                              hipStream_t stream) {
    const int* coords = (const int*)d_in[0];
    const float* feats = (const float*)d_in[1];
    const float* w1 = (const float*)d_in[2];
    const float* w2 = (const float*)d_in[3];
    const float* w3 = (const float*)d_in[4];
    const float* w4 = (const float*)d_in[5];
    const float* fc1w = (const float*)d_in[6];
    const float* fc1b = (const float*)d_in[7];
    const float* fc2w = (const float*)d_in[8];
    const float* fc2b = (const float*)d_in[9];
    float* out = (float*)d_out;
    char* ws = (char*)d_ws;
    float* x0 = (float*)(ws + OFF_X0);
    unsigned* m0b = (unsigned*)(ws + OFF_M0B);
    float* y1 = (float*)(ws + OFF_Y1);
    unsigned char* m1g = (unsigned char*)(ws + OFF_M1);
    float* y2 = (float*)(ws + OFF_Y2);
    unsigned char* m2g = (unsigned char*)(ws + OFF_M2);
    float* y3 = (float*)(ws + OFF_Y3);
    unsigned char* m3g = (unsigned char*)(ws + OFF_M3);
    float* y4 = (float*)(ws + OFF_Y4);
    float* h1 = (float*)(ws + OFF_H1);
    float* p4 = (float*)(ws + OFF_P4);
    int P = in_sizes[1];

    // zero x0 + m0 bitfield (covers aliased y2..p4 regions too)
    hipMemsetAsync(ws, 0, OFF_Y1, stream);
    k_scatter<<<(P + 255) / 256, 256, 0, stream>>>(coords, feats, x0, m0b, P);
    k_l1<<<(S1 * S1) / 256, 256, 0, stream>>>(x0, m0b, w1, y1, m1g);
    k_l2<<<S2 * S2, 64, 0, stream>>>(y1, m1g, w2, y2, m2g);
    k_l3<<<S3 * S3, 128, 0, stream>>>(y2, m2g, w3, y3, m3g);
    k_l4<<<S4 * S4 * 5, 256, 0, stream>>>(y3, w4, p4);
    k_p4<<<S4 * S4, 256, 0, stream>>>(p4, m3g, y4);
    k_fc1<<<32, 256, 0, stream>>>(y4, fc1w, h1);
    k_fc2<<<1, 64, 0, stream>>>(h1, fc1b, fc2w, fc2b, out);
}